// Round 15
// baseline (123.121 us; speedup 1.0000x reference)
//
#include <hip/hip_runtime.h>
#include <math.h>

#define N_PATHS 23
#define HIDDEN  32
#define N_NODES 4096
#define N_EDGES 8192
#define FEAT    512
#define BLK     64    // 1 wave/block; 8 edges/wave, two 32x32 n-tiles
#define ZERO_BLOCKS 256

// wave-local LDS phase separator (all prior DS ops complete)
#define WAVE_SYNC() asm volatile("s_waitcnt lgkmcnt(0)" ::: "memory")

typedef __attribute__((ext_vector_type(8)))  short bf16x8;
typedef __attribute__((ext_vector_type(16))) float f32x16;

// ---- compile-time path metadata (PATHS enumeration: l1 outer, l2, l3) ----
constexpr int cL1[N_PATHS] = {0,0,0,0, 1,1,1,1,1,1, 2,2,2,2,2,2,2, 3,3,3,3,3,3};
constexpr int cL2[N_PATHS] = {0,1,2,3, 0,1,1,2,2,3, 0,1,1,2,2,3,3, 0,1,2,2,3,3};
constexpr int cCOFF[N_PATHS]= {0,1,10,35,84,93,102,147,192,297,402,427,472,577,602,727,832,1077,1126,1231,1336,1581,1630};
constexpr int cL3P[N_PATHS] = {0,5,13,21, 1,4,7,11,15,19, 2,6,9,10,14,18,22, 3,8,12,16,17,20};
constexpr int cL3S[5] = {0,4,10,17,23};
constexpr int cOFF3[4] = {0,32,128,288};
__device__ const int CNT_L3[4] = {4,6,7,6};
__device__ const int D_L3[N_PATHS] = {0,1,2,3, 1,0,2,1,3,2, 2,1,3,0,2,1,3, 3,2,1,3,0,2};

// ---- 8-point Gauss-Legendre nodes/weights (128-pt rule: exact for degree<=9 SH triple products) ----
__device__ const double GLX8[8] = {
    -0.96028985649753623168, -0.79666647741362673959, -0.52553240991632898582, -0.18343464249564980494,
     0.18343464249564980494,  0.52553240991632898582,  0.79666647741362673959,  0.96028985649753623168};
__device__ const double GLW8[8] = {
     0.10122853629037625915,  0.22238103445337447054,  0.31370664587788728734,  0.36268378337836198297,
     0.36268378337836198297,  0.31370664587788728734,  0.22238103445337447054,  0.10122853629037625915};
// cos/sin(k*pi/8), k=0..15 — exact literals
__device__ const double COSP16[16] = {
  1.0,                     0.92387953251128675613,  0.70710678118654752440,  0.38268343236508977173,
  0.0,                    -0.38268343236508977173, -0.70710678118654752440, -0.92387953251128675613,
 -1.0,                    -0.92387953251128675613, -0.70710678118654752440, -0.38268343236508977173,
  0.0,                     0.38268343236508977173,  0.70710678118654752440,  0.92387953251128675613};
__device__ const double SINP16[16] = {
  0.0,                     0.38268343236508977173,  0.70710678118654752440,  0.92387953251128675613,
  1.0,                     0.92387953251128675613,  0.70710678118654752440,  0.38268343236508977173,
  0.0,                    -0.38268343236508977173, -0.70710678118654752440, -0.92387953251128675613,
 -1.0,                    -0.92387953251128675613, -0.70710678118654752440, -0.38268343236508977173};

__device__ inline void sh_f64(double x, double y, double z, double* Y) {
    const double s3 = 1.7320508075688772935, s5 = 2.2360679774997896964,
                 s7 = 2.6457513110645905905, s15 = 3.8729833462074168852;
    const double c58 = 0.79056941504209483300, c38 = 0.61237243569579452455;
    Y[0] = 1.0;
    Y[1] = s3*x;  Y[2] = s3*y;  Y[3] = s3*z;
    Y[4] = s5*s3*x*z;  Y[5] = s5*s3*x*y;
    Y[6] = s5*(y*y - 0.5*(x*x + z*z));
    Y[7] = s5*s3*y*z;  Y[8] = s5*(s3/2.0)*(z*z - x*x);
    Y[9] = s7*c58*x*(3.0*z*z - x*x);
    Y[10]= s7*s15*x*y*z;
    Y[11]= s7*c38*x*(5.0*y*y - 1.0);
    Y[12]= s7*0.5*y*(5.0*y*y - 3.0);
    Y[13]= s7*c38*z*(5.0*y*y - 1.0);
    Y[14]= s7*(s15/2.0)*y*(z*z - x*x);
    Y[15]= s7*c58*z*(z*z - 3.0*x*x);
}

__device__ inline void sh_f32(float x, float y, float z, float* Y) {
    const float s3 = 1.73205080757f, s5 = 2.23606797750f, s7 = 2.64575131106f, s15 = 3.87298334621f;
    const float c58 = 0.79056941504f, c38 = 0.61237243570f;
    Y[0] = 1.0f;
    Y[1] = s3*x;  Y[2] = s3*y;  Y[3] = s3*z;
    Y[4] = s15*x*z;  Y[5] = s15*x*y;
    Y[6] = s5*(y*y - 0.5f*(x*x + z*z));
    Y[7] = s15*y*z;  Y[8] = s5*(s3*0.5f)*(z*z - x*x);
    Y[9] = s7*c58*x*(3.0f*z*z - x*x);
    Y[10]= s7*s15*x*y*z;
    Y[11]= s7*c38*x*(5.0f*y*y - 1.0f);
    Y[12]= s7*0.5f*y*(5.0f*y*y - 3.0f);
    Y[13]= s7*c38*z*(5.0f*y*y - 1.0f);
    Y[14]= s7*(s15*0.5f)*y*(z*z - x*x);
    Y[15]= s7*c58*z*(z*z - 3.0f*x*x);
}

__device__ inline unsigned short bf16rne(float x) {
    unsigned int u = __float_as_uint(x);
    unsigned int r = (u + 0x7FFFu + ((u >> 16) & 1u)) >> 16;
    return (unsigned short)r;
}
__device__ inline float bf16f(unsigned short h) {
    return __uint_as_float(((unsigned int)h) << 16);
}

// ---- setup: W3J tables (128-pt quadrature) + weight transpose + output zeroing ----
__global__ __launch_bounds__(512) void w3j_setup_kernel(
    const float* __restrict__ ww, const float* __restrict__ wb,
    float* __restrict__ g_w3j,
    unsigned short* __restrict__ Awhi, unsigned short* __restrict__ Awlo,
    unsigned short* __restrict__ Abhi, unsigned short* __restrict__ Ablo,
    float* __restrict__ out) {
    const int t = threadIdx.x;

    if (blockIdx.x >= N_PATHS) {   // zero-blocks
        const int b = blockIdx.x - N_PATHS;
        float4* o4 = (float4*)(out + (size_t)b * (N_NODES*FEAT/ZERO_BLOCKS));
#pragma unroll
        for (int r = 0; r < 4; ++r)
            o4[t + 512*r] = make_float4(0.f,0.f,0.f,0.f);
        return;
    }

    __shared__ float s_Yq[128][17];
    __shared__ float s_wq[128];
    __shared__ float s_part[256];
    __shared__ float red[256];
    __shared__ float s_scale;

    const int p = blockIdx.x;
    const int l1 = cL1[p], l2 = cL2[p];
    const int l3 = D_L3[p];
    const int d2 = 2*l2+1, d3 = 2*l3+1;
    const int csize = (2*l1+1)*d2*d3;
    const double step = 2.0*3.14159265358979323846/16.0;

    // weight transpose to A-layout [p][w][u], bf16 hi/lo split
#pragma unroll
    for (int r = 0; r < 2; ++r) {
        const int idx = t + 512*r;
        const int w = idx >> 5, u = idx & 31;
        const float vw = ww[p*1024 + u*32 + w];
        const float vb = wb[p*1024 + u*32 + w];
        const unsigned short hw = bf16rne(vw);
        const unsigned short hb = bf16rne(vb);
        const int o = p*1024 + w*32 + u;
        Awhi[o] = hw;  Awlo[o] = bf16rne(vw - bf16f(hw));
        Abhi[o] = hb;  Ablo[o] = bf16rne(vb - bf16f(hb));
    }

    // phase A: one quadrature point per thread (first 128 threads)
    if (t < 128) {
        const int iu = t >> 4, ip = t & 15;
        const double u = GLX8[iu];
        const double st = sqrt(fmax(1.0 - u*u, 0.0));
        double Y[16];
        sh_f64(st*COSP16[ip], st*SINP16[ip], u, Y);
#pragma unroll
        for (int i = 0; i < 16; ++i) s_Yq[t][i] = (float)Y[i];
        s_wq[t] = (float)(GLW8[iu] * step);
    }
    __syncthreads();

    // phase B: 4 threads/entry, 32 interleaved points each, shuffle-reduce
    const int entry0 = t >> 2, sub = t & 3;
#pragma unroll
    for (int pass = 0; pass < 2; ++pass) {
        const int entry = entry0 + pass*128;
        float acc = 0.f;
        if (entry < csize) {
            const int i = entry/(d2*d3); const int r = entry - i*(d2*d3);
            const int j = r/d3; const int k = r - j*d3;
            const int ai = l1*l1+i, bi = l2*l2+j, ci = l3*l3+k;
#pragma unroll 4
            for (int it = 0; it < 32; ++it) {
                const int q = it*4 + sub;
                acc = fmaf(s_wq[q] * s_Yq[q][ai] * s_Yq[q][bi], s_Yq[q][ci], acc);
            }
        }
        acc += __shfl_xor(acc, 1);
        acc += __shfl_xor(acc, 2);
        if (sub == 0 && entry < csize) s_part[entry] = acc;
    }
    __syncthreads();

    if (t < 256) { const float v = (t < csize) ? s_part[t] : 0.f; red[t] = v*v; }
    __syncthreads();
    for (int s = 128; s > 0; s >>= 1) {
        if (t < s) red[t] += red[t+s];
        __syncthreads();
    }
    if (t == 0) {
        const float pw = sqrtf((float)(2*l3+1) / ((float)CNT_L3[l3] * (float)HIDDEN));
        s_scale = pw / sqrtf(red[0]);
    }
    __syncthreads();
    if (t < csize) g_w3j[cCOFF[p] + t] = s_part[t] * s_scale;
}

// ---- one path: z(8 edges) -> A prefetch -> tmp(4 u-rows/lane) -> 2x 32x32 MFMA ----
template<int G, int P>
__device__ __forceinline__ void do_path(
    int lane, int el8, int u3, int bvoff, int avaddr,
    const float (&xr)[4][16],
    const float* __restrict__ w3j,
    const unsigned short* __restrict__ Awhi, const unsigned short* __restrict__ Awlo,
    const unsigned short* __restrict__ Abhi, const unsigned short* __restrict__ Ablo,
    const float* sY, float* sz,
    unsigned short (*sbh)[1280], unsigned short (*sbl)[1280],
    f32x16 (&Cw)[2], f32x16 (&Cb)[2])
{
    constexpr int l1 = cL1[P], l2 = cL2[P];
    constexpr int d1 = 2*l1+1, d2 = 2*l2+1, d3 = 2*G+1;
    constexpr int zc = d1*d3;
    constexpr int xo = l1*l1;

    // z[el][i][k] = sum_j Y[el][l2^2+j] * C[i][j][k]   (8 edges; C via L1)
#pragma unroll
    for (int base = 0; base < 8*zc; base += 64) {
        const int idx = base + lane;
        if (idx < 8*zc) {
            const int elz = idx / zc;          // const-div
            const int r = idx - elz*zc;
            const int i = r / d3, k = r - i*d3;
            const float* Cp = w3j + cCOFF[P] + i*(d2*d3) + k;
            const float* Yp = sY + elz*16 + l2*l2;
            float acc = 0.f;
#pragma unroll
            for (int j = 0; j < d2; ++j) acc = fmaf(Yp[j], Cp[j*d3], acc);
            sz[idx] = acc;
        }
    }
    WAVE_SYNC();

    // A-operand prefetch (global/L2) BEFORE the tmp VALU block hides its latency
    // (shared by BOTH n-tiles — the per-path fixed cost amortized over 8 edges)
    const unsigned short* pwh = Awhi + P*1024;
    const unsigned short* pwl = Awlo + P*1024;
    const unsigned short* pbh = Abhi + P*1024;
    const unsigned short* pbl = Ablo + P*1024;
    bf16x8 awh[2], awl[2], abh[2], abl[2];
#pragma unroll
    for (int kc = 0; kc < 2; ++kc) {
        awh[kc] = *(const bf16x8*)(pwh + avaddr + kc*16);
        awl[kc] = *(const bf16x8*)(pwl + avaddr + kc*16);
        abh[kc] = *(const bf16x8*)(pbh + avaddr + kc*16);
        abl[kc] = *(const bf16x8*)(pbl + avaddr + kc*16);
    }

    // tmp[u][k] = sum_i x[u,i]*z[i,k] for u = 4*u3..4*u3+3; chop-split; packed u32 stores
    {
        const float* zr = sz + el8*zc;
        const int tile = el8 >> 2, elL = el8 & 3;
        unsigned short* bh = sbh[tile] + (elL*d3)*40 + 4*u3;
        unsigned short* bl = sbl[tile] + (elL*d3)*40 + 4*u3;
#pragma unroll
        for (int k = 0; k < d3; ++k) {
            float tv[4] = {0.f, 0.f, 0.f, 0.f};
#pragma unroll
            for (int i = 0; i < d1; ++i) {
                const float zz = zr[i*d3 + k];
#pragma unroll
                for (int r = 0; r < 4; ++r) tv[r] = fmaf(xr[r][xo+i], zz, tv[r]);
            }
            unsigned int hi01, hi23, lo01, lo23;
            {
                const unsigned int b0 = __float_as_uint(tv[0]);
                const unsigned int b1 = __float_as_uint(tv[1]);
                const unsigned int b2 = __float_as_uint(tv[2]);
                const unsigned int b3 = __float_as_uint(tv[3]);
                const float l0 = tv[0] - __uint_as_float(b0 & 0xFFFF0000u);
                const float l1f = tv[1] - __uint_as_float(b1 & 0xFFFF0000u);
                const float l2f = tv[2] - __uint_as_float(b2 & 0xFFFF0000u);
                const float l3f = tv[3] - __uint_as_float(b3 & 0xFFFF0000u);
                hi01 = (b0 >> 16) | (b1 & 0xFFFF0000u);
                hi23 = (b2 >> 16) | (b3 & 0xFFFF0000u);
                lo01 = (__float_as_uint(l0) >> 16) | (__float_as_uint(l1f) & 0xFFFF0000u);
                lo23 = (__float_as_uint(l2f) >> 16) | (__float_as_uint(l3f) & 0xFFFF0000u);
            }
            *(unsigned int*)(bh + k*40)     = hi01;
            *(unsigned int*)(bh + k*40 + 2) = hi23;
            *(unsigned int*)(bl + k*40)     = lo01;
            *(unsigned int*)(bl + k*40 + 2) = lo23;
        }
    }
    WAVE_SYNC();

    // B loads + 24 MFMA (2 tiles x 2 K-chunks x 3-pass hi/lo x {w,b}), 4 interleaved chains
#pragma unroll
    for (int kc = 0; kc < 2; ++kc) {
        const bf16x8 bh0 = *(const bf16x8*)(sbh[0] + bvoff + kc*16);
        const bf16x8 bl0 = *(const bf16x8*)(sbl[0] + bvoff + kc*16);
        const bf16x8 bh1 = *(const bf16x8*)(sbh[1] + bvoff + kc*16);
        const bf16x8 bl1 = *(const bf16x8*)(sbl[1] + bvoff + kc*16);
        Cw[0] = __builtin_amdgcn_mfma_f32_32x32x16_bf16(awh[kc], bh0, Cw[0], 0, 0, 0);
        Cw[1] = __builtin_amdgcn_mfma_f32_32x32x16_bf16(awh[kc], bh1, Cw[1], 0, 0, 0);
        Cb[0] = __builtin_amdgcn_mfma_f32_32x32x16_bf16(abh[kc], bh0, Cb[0], 0, 0, 0);
        Cb[1] = __builtin_amdgcn_mfma_f32_32x32x16_bf16(abh[kc], bh1, Cb[1], 0, 0, 0);
        Cw[0] = __builtin_amdgcn_mfma_f32_32x32x16_bf16(awh[kc], bl0, Cw[0], 0, 0, 0);
        Cw[1] = __builtin_amdgcn_mfma_f32_32x32x16_bf16(awh[kc], bl1, Cw[1], 0, 0, 0);
        Cb[0] = __builtin_amdgcn_mfma_f32_32x32x16_bf16(abh[kc], bl0, Cb[0], 0, 0, 0);
        Cb[1] = __builtin_amdgcn_mfma_f32_32x32x16_bf16(abh[kc], bl1, Cb[1], 0, 0, 0);
        Cw[0] = __builtin_amdgcn_mfma_f32_32x32x16_bf16(awl[kc], bh0, Cw[0], 0, 0, 0);
        Cw[1] = __builtin_amdgcn_mfma_f32_32x32x16_bf16(awl[kc], bh1, Cw[1], 0, 0, 0);
        Cb[0] = __builtin_amdgcn_mfma_f32_32x32x16_bf16(abl[kc], bh0, Cb[0], 0, 0, 0);
        Cb[1] = __builtin_amdgcn_mfma_f32_32x32x16_bf16(abl[kc], bh1, Cb[1], 0, 0, 0);
    }
    WAVE_SYNC();  // B reads done before next path's stage overwrites
}

// ---- one l3 group: its paths + epilogue into s_msg ----
template<int G>
__device__ __forceinline__ void do_group(
    int lane, int el8, int u3, int bvoff, int avaddr,
    const float (&xr)[4][16],
    const float* __restrict__ w3j,
    const unsigned short* __restrict__ Awhi, const unsigned short* __restrict__ Awlo,
    const unsigned short* __restrict__ Abhi, const unsigned short* __restrict__ Ablo,
    const float* sY, float* sz,
    unsigned short (*sbh)[1280], unsigned short (*sbl)[1280],
    const float* slen, float* smsg)
{
    constexpr int d3 = 2*G+1;
    constexpr int s = cL3S[G];
    constexpr int n = cL3S[G+1] - cL3S[G];
    f32x16 Cw[2], Cb[2];
    Cw[0] = (f32x16)(0.f); Cw[1] = (f32x16)(0.f);
    Cb[0] = (f32x16)(0.f); Cb[1] = (f32x16)(0.f);

    do_path<G, cL3P[s+0]>(lane,el8,u3,bvoff,avaddr,xr,w3j,Awhi,Awlo,Abhi,Ablo,sY,sz,sbh,sbl,Cw,Cb);
    do_path<G, cL3P[s+1]>(lane,el8,u3,bvoff,avaddr,xr,w3j,Awhi,Awlo,Abhi,Ablo,sY,sz,sbh,sbl,Cw,Cb);
    do_path<G, cL3P[s+2]>(lane,el8,u3,bvoff,avaddr,xr,w3j,Awhi,Awlo,Abhi,Ablo,sY,sz,sbh,sbl,Cw,Cb);
    do_path<G, cL3P[s+3]>(lane,el8,u3,bvoff,avaddr,xr,w3j,Awhi,Awlo,Abhi,Ablo,sY,sz,sbh,sbl,Cw,Cb);
    if constexpr (n > 4)
        do_path<G, cL3P[s+4]>(lane,el8,u3,bvoff,avaddr,xr,w3j,Awhi,Awlo,Abhi,Ablo,sY,sz,sbh,sbl,Cw,Cb);
    if constexpr (n > 5)
        do_path<G, cL3P[s+5]>(lane,el8,u3,bvoff,avaddr,xr,w3j,Awhi,Awlo,Abhi,Ablo,sY,sz,sbh,sbl,Cw,Cb);
    if constexpr (n > 6)
        do_path<G, cL3P[s+6]>(lane,el8,u3,bvoff,avaddr,xr,w3j,Awhi,Awlo,Abhi,Ablo,sY,sz,sbh,sbl,Cw,Cb);

    // epilogue: msg = len*Cw + Cb, both tiles
    // C/D layout (verified m74/m101): col=lane&31, row=(reg&3)+8*(reg>>2)+4*(lane>>5)
    const int col = lane & 31;
    if (col < 4*d3) {
        const int elcL = col / d3, k = col - elcL*d3;   // const-div
#pragma unroll
        for (int tile = 0; tile < 2; ++tile) {
            const int elc = tile*4 + elcL;
            const float len = slen[elc];
            float* mp = smsg + elc*FEAT + cOFF3[G] + k;
#pragma unroll
            for (int reg = 0; reg < 16; ++reg) {
                const int w = (reg & 3) + 8*(reg >> 2) + 4*(lane >> 5);
                mp[w*d3] = fmaf(len, Cw[tile][reg], Cb[tile][reg]);
            }
        }
    }
}

// ---- main: 1 wave/block, 8 edges/wave, two 32x32 n-tiles ----
__global__ __launch_bounds__(BLK) void edge_kernel(
    const float* __restrict__ nf,
    const int*   __restrict__ eidx,
    const float* __restrict__ ev,
    const float* __restrict__ w3j,
    const unsigned short* __restrict__ Awhi,
    const unsigned short* __restrict__ Awlo,
    const unsigned short* __restrict__ Abhi,
    const unsigned short* __restrict__ Ablo,
    float*       __restrict__ out)
{
    __shared__ float s_zp[8*49];         // per-path z, 8 edges
    __shared__ float s_Y[8*16];
    __shared__ float s_len[8];
    __shared__ int   s_src[8];
    __shared__ int   s_dst[8];
    __shared__ __align__(16) unsigned short s_Bhi[2][1280];  // per-tile [col(32)][u(32)+pad8]
    __shared__ __align__(16) unsigned short s_Blo[2][1280];
    __shared__ float s_msg[8*FEAT];      // 16 KB

    const int lane = threadIdx.x;
    const int el8  = lane >> 3;      // tmp-phase edge (8 per wave)
    const int u3   = lane & 7;       // tmp-phase u-quad index (u = 4*u3..4*u3+3)
    const int e0   = blockIdx.x * 8;
    const int bvoff  = (lane & 31)*40 + (lane >> 5)*8;   // B: n=lane&31, k0=(lane>>5)*8
    const int avaddr = (lane & 31)*32 + (lane >> 5)*8;   // A: m=lane&31, k0=(lane>>5)*8

    if (lane < 8) {
        const int e = e0 + lane;
        s_src[lane] = eidx[e];
        s_dst[lane] = eidx[N_EDGES + e];
        const float x = ev[e*3+0], y = ev[e*3+1], z = ev[e*3+2];
        const float len = sqrtf(x*x + y*y + z*z);
        const float lc = fmaxf(len, 1e-8f);
        s_len[lane] = lc;
        float Yl[16];
        sh_f32(x/lc, y/lc, z/lc, Yl);
#pragma unroll
        for (int i = 0; i < 16; ++i) s_Y[lane*16+i] = Yl[i];
    }
    WAVE_SYNC();

    // preload this lane's 4 u-rows of x (u = 4*u3 + r) into registers (64 VGPRs)
    float xr[4][16];
    {
        const float* xrow = nf + (size_t)s_src[el8]*FEAT;
#pragma unroll
        for (int r = 0; r < 4; ++r) {
            const int u = 4*u3 + r;
            xr[r][0] = xrow[u];
#pragma unroll
            for (int i = 0; i < 3; ++i) xr[r][1+i] = xrow[32 + u*3 + i];
#pragma unroll
            for (int i = 0; i < 5; ++i) xr[r][4+i] = xrow[128 + u*5 + i];
#pragma unroll
            for (int i = 0; i < 7; ++i) xr[r][9+i] = xrow[288 + u*7 + i];
        }
    }

    do_group<0>(lane,el8,u3,bvoff,avaddr,xr,w3j,Awhi,Awlo,Abhi,Ablo,
                s_Y, s_zp, s_Bhi, s_Blo, s_len, s_msg);
    do_group<1>(lane,el8,u3,bvoff,avaddr,xr,w3j,Awhi,Awlo,Abhi,Ablo,
                s_Y, s_zp, s_Bhi, s_Blo, s_len, s_msg);
    do_group<2>(lane,el8,u3,bvoff,avaddr,xr,w3j,Awhi,Awlo,Abhi,Ablo,
                s_Y, s_zp, s_Bhi, s_Blo, s_len, s_msg);
    do_group<3>(lane,el8,u3,bvoff,avaddr,xr,w3j,Awhi,Awlo,Abhi,Ablo,
                s_Y, s_zp, s_Bhi, s_Blo, s_len, s_msg);
    WAVE_SYNC();

    // wave-local coalesced scatter: 8 edges x 512 contiguous (proven actor pattern)
    for (int i = lane; i < 8*FEAT; i += 64) {
        const int elc = i >> 9, m = i & 511;
        atomicAdd(&out[(size_t)s_dst[elc]*FEAT + m], s_msg[i]);
    }
}

extern "C" void kernel_launch(void* const* d_in, const int* in_sizes, int n_in,
                              void* d_out, int out_size, void* d_ws, size_t ws_size,
                              hipStream_t stream) {
    const float* nf   = (const float*)d_in[0];
    const int*   eidx = (const int*)  d_in[1];
    const float* ev   = (const float*)d_in[2];
    const float* ww   = (const float*)d_in[3];
    const float* wb   = (const float*)d_in[4];
    float* out = (float*)d_out;

    float* w3j = (float*)d_ws;                                   // 7500 B
    unsigned short* Awhi = (unsigned short*)((char*)d_ws + 16384);
    unsigned short* Awlo = Awhi + N_PATHS*1024;
    unsigned short* Abhi = Awlo + N_PATHS*1024;
    unsigned short* Ablo = Abhi + N_PATHS*1024;                  // ends at 204800 B

    w3j_setup_kernel<<<N_PATHS + ZERO_BLOCKS, 512, 0, stream>>>(
        ww, wb, w3j, Awhi, Awlo, Abhi, Ablo, out);
    edge_kernel<<<N_EDGES/8, BLK, 0, stream>>>(nf, eidx, ev, w3j, Awhi, Awlo, Abhi, Ablo, out);
}